// Round 1
// baseline (516.098 us; speedup 1.0000x reference)
//
#include <hip/hip_runtime.h>
#include <cmath>

// Bahdanau attention, MI355X.
// B=32, T=8192, D=256, U=128, fp32 in/out.
// Strategy: single pass over values (268 MB = the HBM floor ~43us).
//  k0: W1 -> bf16 hi/lo split, stored in MFMA B-fragment layout (ws).
//  k1: h_q = relu(query@W2 + b2)  (tiny).
//  k2: per (b, 64-row chunk): stage values chunk to LDS as bf16 hi/lo in
//      A-fragment layout; 16x16x32 bf16 MFMA with 3-term split (hi*hi +
//      hi*lo + lo*hi) => fp32-accurate h_v; epilogue relu/+hq/tanh/*V ->
//      scores; chunk-local softmax stats + partial context from LDS copy.
//  k3: per b: combine chunk stats -> global softmax; write attn + context.

#define B_ 32
#define T_ 8192
#define D_ 256
#define U_ 128
#define CH_ 64             // t-rows per block in k2
#define NCH_ (T_ / CH_)    // 128 chunks per batch
#define GRP_ 520           // ushort stride per (mtile,kk) group: 64*8 + 8 pad

typedef float f32x4 __attribute__((ext_vector_type(4)));
typedef short s16x8 __attribute__((ext_vector_type(8)));
typedef __bf16 bf16x8 __attribute__((ext_vector_type(8)));

__device__ __forceinline__ unsigned short f2bf(float x) {
    unsigned u = __builtin_bit_cast(unsigned, x);
    u += 0x7fffu + ((u >> 16) & 1u);     // RNE
    return (unsigned short)(u >> 16);
}
__device__ __forceinline__ float bf2f(unsigned short s) {
    return __builtin_bit_cast(float, ((unsigned)s) << 16);
}

// ---------------- k0: W1 -> hi/lo bf16 in B-fragment layout ----------------
// frag element idx = ((kk*8+nn)*64 + lane)*8 + j
// maps to W1[k][n], k = kk*32 + (lane>>4)*8 + j, n = nn*16 + (lane&15)
__global__ void prep_w1(const float* __restrict__ W1,
                        unsigned short* __restrict__ W1h,
                        unsigned short* __restrict__ W1l) {
    int idx = blockIdx.x * 256 + threadIdx.x;   // 32768 total
    int j = idx & 7, lane = (idx >> 3) & 63, nn = (idx >> 9) & 7, kk = idx >> 12;
    int k = kk * 32 + (lane >> 4) * 8 + j;
    int n = nn * 16 + (lane & 15);
    float w = W1[k * U_ + n];
    unsigned short hi = f2bf(w);
    W1h[idx] = hi;
    W1l[idx] = f2bf(w - bf2f(hi));
}

// ---------------- k1: h_q = relu(query @ W2 + b2) ----------------
__global__ void prep_hq(const float* __restrict__ query, const float* __restrict__ W2,
                        const float* __restrict__ W2b, float* __restrict__ hq) {
    int b = blockIdx.x, u = threadIdx.x;
    float acc = W2b[u];
    const float* q = query + b * D_;
    for (int d = 0; d < D_; ++d) acc = fmaf(q[d], W2[d * U_ + u], acc);
    hq[b * U_ + u] = fmaxf(acc, 0.f);
}

// ---------------- k2: fused scores + chunk softmax + partial context -------
__global__ __launch_bounds__(256, 2) void score_ctx(
    const float* __restrict__ values,
    const unsigned short* __restrict__ W1h, const unsigned short* __restrict__ W1l,
    const float* __restrict__ hq, const float* __restrict__ b1,
    const float* __restrict__ Vk,
    float* __restrict__ scores, float* __restrict__ stats, float* __restrict__ ctxp)
{
    __shared__ __align__(16) unsigned short Ah[32 * GRP_];   // 33280 B
    __shared__ __align__(16) unsigned short Al[32 * GRP_];   // 33280 B
    __shared__ float scp[4][CH_];
    __shared__ float sc[CH_];
    __shared__ float esc[CH_];

    const int tid = threadIdx.x;
    const int b = blockIdx.x >> 7;      // NCH_=128 chunks
    const int c = blockIdx.x & 127;
    const int t0 = c * CH_;

    // Phase 1: stage 64x256 fp32 chunk -> bf16 hi/lo in A-fragment layout
    {
        const float* src = values + ((size_t)b * T_ + t0) * D_;
        for (int it = 0; it < 8; ++it) {
            int row = it * 8 + (tid >> 5);      // 0..63
            int col = (tid & 31) * 8;           // 0..248
            const float* p = src + row * D_ + col;
            float4 x0 = *(const float4*)p;
            float4 x1 = *(const float4*)(p + 4);
            float xs[8] = {x0.x, x0.y, x0.z, x0.w, x1.x, x1.y, x1.z, x1.w};
            s16x8 hv, lv;
#pragma unroll
            for (int e = 0; e < 8; ++e) {
                unsigned short hb = f2bf(xs[e]);
                hv[e] = (short)hb;
                lv[e] = (short)f2bf(xs[e] - bf2f(hb));
            }
            int mt = row >> 4, m = row & 15;
            int kk = col >> 5, g = (col >> 3) & 3;
            int off = (mt * 8 + kk) * GRP_ + (g * 16 + m) * 8;
            *(s16x8*)&Ah[off] = hv;
            *(s16x8*)&Al[off] = lv;
        }
    }
    __syncthreads();

    // Phase 2: MFMA. wave w owns N-tiles {2w, 2w+1}; loops all 4 M-tiles.
    const int lane = tid & 63;
    const int w = tid >> 6;
    f32x4 acc[4][2];
#pragma unroll
    for (int mt = 0; mt < 4; ++mt)
#pragma unroll
        for (int q = 0; q < 2; ++q) acc[mt][q] = (f32x4){0.f, 0.f, 0.f, 0.f};

#pragma unroll
    for (int kk = 0; kk < 8; ++kk) {
        bf16x8 bh[2], bl[2];
#pragma unroll
        for (int q = 0; q < 2; ++q) {
            int nn = 2 * w + q;
            int boff = ((kk * 8 + nn) * 64 + lane) * 8;
            bh[q] = __builtin_bit_cast(bf16x8, *(const s16x8*)&W1h[boff]);
            bl[q] = __builtin_bit_cast(bf16x8, *(const s16x8*)&W1l[boff]);
        }
#pragma unroll
        for (int mt = 0; mt < 4; ++mt) {
            int aoff = (mt * 8 + kk) * GRP_ + lane * 8;
            bf16x8 ah = __builtin_bit_cast(bf16x8, *(const s16x8*)&Ah[aoff]);
            bf16x8 al = __builtin_bit_cast(bf16x8, *(const s16x8*)&Al[aoff]);
#pragma unroll
            for (int q = 0; q < 2; ++q) {
                acc[mt][q] = __builtin_amdgcn_mfma_f32_16x16x32_bf16(ah, bh[q], acc[mt][q], 0, 0, 0);
                acc[mt][q] = __builtin_amdgcn_mfma_f32_16x16x32_bf16(ah, bl[q], acc[mt][q], 0, 0, 0);
                acc[mt][q] = __builtin_amdgcn_mfma_f32_16x16x32_bf16(al, bh[q], acc[mt][q], 0, 0, 0);
            }
        }
    }

    // Phase 3: epilogue -> per-wave partial scores (sum over its 32 units)
    {
        int u0 = lane & 15;
        float b1v[2], hqv[2], Vv[2];
#pragma unroll
        for (int q = 0; q < 2; ++q) {
            int u = (2 * w + q) * 16 + u0;
            b1v[q] = b1[u];
            hqv[q] = hq[b * U_ + u];
            Vv[q] = Vk[u];
        }
#pragma unroll
        for (int mt = 0; mt < 4; ++mt) {
            float p[4];
#pragma unroll
            for (int i = 0; i < 4; ++i) {
                float z = 0.f;
#pragma unroll
                for (int q = 0; q < 2; ++q) {
                    float h = fmaxf(acc[mt][q][i] + b1v[q], 0.f) + hqv[q];
                    z += tanhf(h) * Vv[q];
                }
                p[i] = z;
            }
#pragma unroll
            for (int off = 1; off < 16; off <<= 1)
#pragma unroll
                for (int i = 0; i < 4; ++i) p[i] += __shfl_xor(p[i], off, 16);
            if (u0 == 0) {
                int base = mt * 16 + (lane >> 4) * 4;
#pragma unroll
                for (int i = 0; i < 4; ++i) scp[w][base + i] = p[i];
            }
        }
    }
    __syncthreads();

    // Phase 4: chunk softmax stats + partial context
    if (tid < CH_) {
        float s = scp[0][tid] + scp[1][tid] + scp[2][tid] + scp[3][tid];
        sc[tid] = s;
        scores[b * T_ + t0 + tid] = s;
    }
    __syncthreads();
    float mc = -1e30f;
    for (int t = 0; t < CH_; ++t) mc = fmaxf(mc, sc[t]);
    if (tid < CH_) esc[tid] = expf(sc[tid] - mc);
    __syncthreads();
    float lc = 0.f;
    for (int t = 0; t < CH_; ++t) lc += esc[t];

    {   // ctx_partial[d] = sum_t e_t * v(t,d), v reconstructed hi+lo (~fp32)
        int d = tid;
        int kk = d >> 5, g = (d >> 3) & 3, j = d & 7;
        int base = kk * GRP_ + g * 128 + j;   // (g*16)*8 = g*128
        float a = 0.f;
        for (int t = 0; t < CH_; ++t) {
            int off = base + (t >> 4) * (8 * GRP_) + (t & 15) * 8;
            a = fmaf(esc[t], bf2f(Ah[off]) + bf2f(Al[off]), a);
        }
        ctxp[((size_t)(b * NCH_ + c)) * D_ + d] = a;
    }
    if (tid == 0) {
        stats[(b * NCH_ + c) * 2 + 0] = mc;
        stats[(b * NCH_ + c) * 2 + 1] = lc;
    }
}

// ---------------- k3: combine chunks -> attn weights + context ----------------
__global__ void finalize(const float* __restrict__ scores, const float* __restrict__ stats,
                         const float* __restrict__ ctxp, float* __restrict__ out)
{
    __shared__ float mArr[NCH_], lArr[NCH_], wArr[NCH_];
    int b = blockIdx.x, tid = threadIdx.x;
    if (tid < NCH_) {
        mArr[tid] = stats[(b * NCH_ + tid) * 2 + 0];
        lArr[tid] = stats[(b * NCH_ + tid) * 2 + 1];
    }
    __syncthreads();
    float M = -1e30f;
    for (int c2 = 0; c2 < NCH_; ++c2) M = fmaxf(M, mArr[c2]);
    if (tid < NCH_) wArr[tid] = expf(mArr[tid] - M);
    __syncthreads();
    float L = 0.f;
    for (int c2 = 0; c2 < NCH_; ++c2) L += lArr[c2] * wArr[c2];
    float invL = 1.f / L;

    {   // context: out[b][d]
        int d = tid;
        float a = 0.f;
        for (int c2 = 0; c2 < NCH_; ++c2)
            a = fmaf(wArr[c2], ctxp[((size_t)(b * NCH_ + c2)) * D_ + d], a);
        out[b * D_ + d] = a * invL;
    }
    // attention weights: out[B*D + b*T + t]
    float* attn = out + B_ * D_;
    for (int t = tid; t < T_; t += 256)
        attn[(size_t)b * T_ + t] = expf(scores[b * T_ + t] - M) * invL;
}

// ---------------- launch ----------------
extern "C" void kernel_launch(void* const* d_in, const int* in_sizes, int n_in,
                              void* d_out, int out_size, void* d_ws, size_t ws_size,
                              hipStream_t stream)
{
    const float* query = (const float*)d_in[0];
    const float* values = (const float*)d_in[1];
    const float* W1 = (const float*)d_in[2];
    const float* b1 = (const float*)d_in[3];
    const float* W2 = (const float*)d_in[4];
    const float* b2 = (const float*)d_in[5];
    const float* Vk = (const float*)d_in[6];
    // d_in[7] = V_bias: constant shift of all scores, cancels in softmax.
    float* out = (float*)d_out;
    char* ws = (char*)d_ws;

    // ws layout (bytes), total 5,423,104
    float* scores = (float*)(ws + 0);                  // B*T*4       = 1048576
    float* hq     = (float*)(ws + 1048576);            // B*U*4       = 16384
    float* stats  = (float*)(ws + 1064960);            // B*128*2*4   = 32768
    float* ctxp   = (float*)(ws + 1097728);            // B*128*256*4 = 4194304
    unsigned short* W1h = (unsigned short*)(ws + 5292032);   // 65536
    unsigned short* W1l = (unsigned short*)(ws + 5357568);   // 65536

    prep_w1<<<128, 256, 0, stream>>>(W1, W1h, W1l);
    prep_hq<<<B_, U_, 0, stream>>>(query, W2, b2, hq);
    score_ctx<<<B_ * NCH_, 256, 0, stream>>>(values, W1h, W1l, hq, b1, Vk,
                                             scores, stats, ctxp);
    finalize<<<B_, 256, 0, stream>>>(scores, stats, ctxp, out);
}